// Round 20
// baseline (192.940 us; speedup 1.0000x reference)
//
#include <hip/hip_runtime.h>
#include <hip/hip_bf16.h>

#define D       256
#define KCB     16384
#define BNROWS  16384
#define MARGIN  0.15f        // ~6.5 sigma of i8 screening noise
#define ZMAX    5.0f
#define EMAX    0.2f
// FS2U = 2*(ZMAX/127)*(EMAX/127) = 1.2400e-4 ; MARGIN_INT = ceil(MARGIN/FS2U)
#define FS2U    (2.0f * (ZMAX / 127.0f) * (EMAX / 127.0f))
#define MARGIN_INT 1210u
#define IBIAS   8388608      // 2^23

typedef __attribute__((ext_vector_type(4))) int   int4v;
typedef __attribute__((ext_vector_type(4))) float f32x4;
typedef unsigned long long u64;

__device__ __forceinline__ void gload_lds16(const void* g, void* l) {
    __builtin_amdgcn_global_load_lds(
        (const __attribute__((address_space(1))) void*)g,
        (__attribute__((address_space(3))) void*)l, 16, 0, 0);
}

// order-preserving float->u32 map (used only in exact rescore)
__device__ __forceinline__ unsigned fmap(float f) {
    unsigned u = __float_as_uint(f);
    return (u & 0x80000000u) ? ~u : (u | 0x80000000u);
}

__device__ __forceinline__ signed char q8(float x, float s) {
    return (signed char)__float2int_rn(fminf(fmaxf(x * s, -127.f), 127.f));
}

// ---------------------------------------------------------------------------
// prep: blocks [0,4096) -> zquant; blocks [4096,5120) -> proj + fused e8.
// ---------------------------------------------------------------------------
__global__ __launch_bounds__(256) void prep_kernel(
    const float* __restrict__ z, signed char* __restrict__ z8,
    const float* __restrict__ ew, const float* __restrict__ pw,
    const float* __restrict__ pb, float* __restrict__ emb,
    signed char* __restrict__ e8)
{
    __shared__ float Et[64][65];
    __shared__ float Pt[64][65];
    const int tid = threadIdx.x;

    if (blockIdx.x < 4096) {
        const int i = blockIdx.x * 256 + tid;
        float4 v = ((const float4*)z)[i];
        const float s = 127.0f / ZMAX;
        char4 c;
        c.x = q8(v.x, s); c.y = q8(v.y, s); c.z = q8(v.z, s); c.w = q8(v.w, s);
        ((char4*)z8)[i] = c;
        return;
    }

    const int bid = blockIdx.x - 4096;
    const int tc  = tid & 15, tr = tid >> 4;
    const int k0  = (bid >> 2) * 64;
    const int d0  = (bid & 3) * 64;

    float acc[4][4];
#pragma unroll
    for (int a = 0; a < 4; ++a)
#pragma unroll
        for (int b = 0; b < 4; ++b) acc[a][b] = 0.f;

    for (int j0 = 0; j0 < 256; j0 += 64) {
        __syncthreads();
#pragma unroll
        for (int i = 0; i < 4; ++i) {
            const int c = i * 256 + tid;
            const int r = c >> 4, c4 = (c & 15) * 4;
            float4 v = *(const float4*)(ew + (size_t)(k0 + r) * 256 + j0 + c4);
            Et[r][c4 + 0] = v.x; Et[r][c4 + 1] = v.y;
            Et[r][c4 + 2] = v.z; Et[r][c4 + 3] = v.w;
            float4 w = *(const float4*)(pw + (size_t)(d0 + r) * 256 + j0 + c4);
            Pt[r][c4 + 0] = w.x; Pt[r][c4 + 1] = w.y;
            Pt[r][c4 + 2] = w.z; Pt[r][c4 + 3] = w.w;
        }
        __syncthreads();
        for (int j = 0; j < 64; ++j) {
            float ev[4], pv[4];
#pragma unroll
            for (int a = 0; a < 4; ++a) ev[a] = Et[tr * 4 + a][j];
#pragma unroll
            for (int b = 0; b < 4; ++b) pv[b] = Pt[tc * 4 + b][j];
#pragma unroll
            for (int a = 0; a < 4; ++a)
#pragma unroll
                for (int b = 0; b < 4; ++b)
                    acc[a][b] = fmaf(ev[a], pv[b], acc[a][b]);
        }
    }

    const float4 bias = *(const float4*)(pb + d0 + tc * 4);
    const float se = 127.0f / EMAX;
#pragma unroll
    for (int a = 0; a < 4; ++a) {
        float4 o;
        o.x = acc[a][0] + bias.x; o.y = acc[a][1] + bias.y;
        o.z = acc[a][2] + bias.z; o.w = acc[a][3] + bias.w;
        const size_t off = (size_t)(k0 + tr * 4 + a) * 256 + d0 + tc * 4;
        *(float4*)(emb + off) = o;
        char4 c;
        c.x = q8(o.x, se); c.y = q8(o.y, se);
        c.z = q8(o.z, se); c.w = q8(o.w, se);
        *(char4*)(e8 + off) = c;
    }
}

// ---------------------------------------------------------------------------
// snorm: s[k] = ||emb[k]||^2 and s_bi[k] = round(s/FS2U) + 2^23.
// ---------------------------------------------------------------------------
__global__ __launch_bounds__(256) void snorm_kernel(
    const float* __restrict__ emb, float* __restrict__ s,
    int* __restrict__ s_bi)
{
    const int tid = threadIdx.x;
    const int row = blockIdx.x * 64 + (tid >> 2);
    const int qd  = tid & 3;
    const size_t base = (size_t)row * 256;
    float sq = 0.f;
#pragma unroll
    for (int j = 0; j < 16; ++j) {
        const int off = qd * 4 + j * 16;
        float4 v = *(const float4*)(emb + base + off);
        sq = fmaf(v.x, v.x, fmaf(v.y, v.y, fmaf(v.z, v.z, fmaf(v.w, v.w, sq))));
    }
    sq += __shfl_xor(sq, 1);
    sq += __shfl_xor(sq, 2);
    if (qd == 0) {
        s[row]    = sq;
        s_bi[row] = (int)rintf(sq / FS2U) + IBIAS;
    }
}

// ---------------------------------------------------------------------------
// argmin_hi v19 (frozen): persistent blocks, B panel LDS-resident.
// ---------------------------------------------------------------------------
__global__ __launch_bounds__(512, 4) void argmin_hi_kernel(
    const signed char* __restrict__ z8, const signed char* __restrict__ e8,
    const int* __restrict__ s_bi,
    unsigned* __restrict__ partial1, unsigned* __restrict__ partial2)
{
    __shared__ alignas(16) short A_lds[2 * 4096];   // 2 bufs x 8 KB (128 z-rows)
    __shared__ alignas(16) short B_lds[4 * 8192];   // 4 RESIDENT tiles x 16 KB

    const int tid  = threadIdx.x;
    const int lane = tid & 63;
    const int wid  = tid >> 6;
    const int wz   = wid >> 2;
    const int wc   = wid & 3;
    const int lcol = lane & 15;
    const int rhi  = lane >> 4;

    const int bn  = blockIdx.x & 63;
    const int bm0 = blockIdx.x >> 6;     // 0..7
    const size_t n0 = (size_t)bn * 256;

    const int slot  = (((lcol & 1) * 4 + rhi) ^ ((lcol >> 1) & 7)) << 3;
    const int aoff0 = wz * 2048 + (lcol >> 1) * 64 + slot;
    const int boff0 = wc * 2048 + (lcol >> 1) * 64 + slot;

    auto goff = [](int c) {
        const int l = c >> 3, u = (c & 7) ^ (l & 7);
        return (size_t)(2 * l + (u >> 2)) * 256 + (size_t)(u & 3) * 16;
    };
    const size_t gA  = goff(tid);
    const int    cB0 = wid * 128 + lane;
    const int    cB1 = cB0 + 64;
    const size_t gB0 = goff(cB0);
    const size_t gB1 = goff(cB1);

    const char* const e8B = (const char*)e8 + n0 * 256;
    const char*       zc  = (const char*)z8 + (size_t)bm0 * 32768;

#pragma unroll
    for (int t = 0; t < 4; ++t) {
        gload_lds16(e8B + (t << 6) + gB0, (void*)(B_lds + t * 8192 + cB0 * 8));
        gload_lds16(e8B + (t << 6) + gB1, (void*)(B_lds + t * 8192 + cB1 * 8));
    }
    gload_lds16(zc + gA,      (void*)(A_lds + tid * 8));
    gload_lds16(zc + 64 + gA, (void*)(A_lds + 4096 + tid * 8));
    asm volatile("s_waitcnt vmcnt(1)" ::: "memory");
    __builtin_amdgcn_s_barrier();

#define COMPUTE_TILE(ABUF, BT)                                                \
    {                                                                         \
        int4v bq[4];                                                          \
        _Pragma("unroll")                                                     \
        for (int n = 0; n < 4; ++n)                                           \
            bq[n] = *(const int4v*)(A_lds + (ABUF) * 4096 + aoff0 + n * 512); \
        __builtin_amdgcn_s_setprio(1);                                        \
        _Pragma("unroll")                                                     \
        for (int m = 0; m < 4; ++m) {                                         \
            const int4v am = *(const int4v*)(B_lds + (BT) * 8192 + boff0 + m * 512); \
            _Pragma("unroll")                                                 \
            for (int n = 0; n < 4; ++n)                                       \
                acc[m][n] = __builtin_amdgcn_mfma_i32_16x16x64_i8(            \
                    am, bq[n], acc[m][n], 0, 0, 0);                           \
        }                                                                     \
        __builtin_amdgcn_s_setprio(0);                                        \
    }

#pragma unroll 1
    for (int i = 0; i < 16; ++i) {
        const bool more = (i < 15);

        int4v acc[4][4];
        const int4v izero = {0, 0, 0, 0};
#pragma unroll
        for (int m = 0; m < 4; ++m)
#pragma unroll
            for (int n = 0; n < 4; ++n) acc[m][n] = izero;

        COMPUTE_TILE(0, 0)
        asm volatile("s_waitcnt vmcnt(0)" ::: "memory");
        __builtin_amdgcn_s_barrier();

        gload_lds16(zc + 128 + gA, (void*)(A_lds + tid * 8));
        COMPUTE_TILE(1, 1)
        asm volatile("s_waitcnt vmcnt(0)" ::: "memory");
        __builtin_amdgcn_s_barrier();

        gload_lds16(zc + 192 + gA, (void*)(A_lds + 4096 + tid * 8));
        COMPUTE_TILE(0, 2)
        asm volatile("s_waitcnt vmcnt(0)" ::: "memory");
        __builtin_amdgcn_s_barrier();

        if (more) gload_lds16(zc + 262144 + gA, (void*)(A_lds + tid * 8));
        COMPUTE_TILE(1, 3)
        __builtin_amdgcn_s_barrier();

        int4v sb[4];
#pragma unroll
        for (int mc = 0; mc < 4; ++mc)
            sb[mc] = *(const int4v*)(s_bi + n0 + wc * 64 + mc * 16 + rhi * 4);

        u64* cand = (u64*)(A_lds + 4096);
#pragma unroll
        for (int nz = 0; nz < 4; ++nz) {
            unsigned v[16];
#pragma unroll
            for (int mc = 0; mc < 4; ++mc) {
                const unsigned cb = (unsigned)(wc * 64 + mc * 16 + rhi * 4);
#pragma unroll
                for (int j = 0; j < 4; ++j)
                    v[mc * 4 + j] =
                        ((unsigned)(sb[mc][j] - acc[mc][nz][j]) << 8) | (cb + j);
            }
            unsigned p1 = min(v[0], v[1]), p2 = max(v[0], v[1]);
#pragma unroll
            for (int q = 1; q < 8; ++q) {
                const unsigned l = min(v[2 * q], v[2 * q + 1]);
                const unsigned h = max(v[2 * q], v[2 * q + 1]);
                const unsigned t = max(p1, l);
                p1 = min(p1, l);
                p2 = min(t, min(p2, h));
            }
#pragma unroll
            for (int mask = 16; mask <= 32; mask <<= 1) {
                const unsigned q1 = __shfl_xor(p1, mask);
                const unsigned q2 = __shfl_xor(p2, mask);
                const unsigned t  = max(p1, q1);
                p1 = min(p1, q1);
                p2 = min(t, min(p2, q2));
            }
            if (rhi == 0) {
                const int row = wz * 64 + nz * 16 + lcol;
                cand[row * 4 + wc] = (u64)p1 | ((u64)p2 << 32);
            }
        }
        __syncthreads();
        if (tid < 128) {
            const u64* c4 = cand + (size_t)tid * 4;
            u64 a = c4[0];
            unsigned p1 = (unsigned)a, p2 = (unsigned)(a >> 32);
#pragma unroll
            for (int w = 1; w < 4; ++w) {
                a = c4[w];
                const unsigned q1 = (unsigned)a, q2 = (unsigned)(a >> 32);
                const unsigned t  = max(p1, q1);
                p1 = min(p1, q1);
                p2 = min(t, min(p2, q2));
            }
            const size_t r0 = (size_t)(bm0 + 8 * i) * 128;
            partial1[(size_t)bn * BNROWS + r0 + tid] = p1;
            partial2[(size_t)bn * BNROWS + r0 + tid] = p2;
        }
        __syncthreads();

        if (more) gload_lds16(zc + 262144 + 64 + gA, (void*)(A_lds + 4096 + tid * 8));
        zc += 262144;
    }
#undef COMPUTE_TILE
}

// ---------------------------------------------------------------------------
// collect_rescore v20: 256 blocks x 64 rows. Coalesced partial staging into
// padded LDS (the old per-row kernel did 2M scattered 4B gathers at 64KB
// stride); per-wave (16 rows each): wave-min -> integer threshold ->
// ballot+popcount compaction (<=32 cands) -> wave-parallel exact fp32
// rescore -> fused finalize (outz/outq float4 coalesced, outidx).
// ---------------------------------------------------------------------------
__global__ __launch_bounds__(256) void collect_rescore_kernel(
    const unsigned* __restrict__ partial1, const unsigned* __restrict__ partial2,
    const float* __restrict__ z, const float* __restrict__ emb,
    const float* __restrict__ s,
    float* __restrict__ outz, float* __restrict__ outq,
    float* __restrict__ outidx)
{
    __shared__ unsigned p1s[64][65];
    __shared__ unsigned p2s[64][65];
    __shared__ int      cands[64][32];
    __shared__ int      kfin[64];

    const int tid     = threadIdx.x;
    const int rowbase = blockIdx.x * 64;
    const int lane    = tid & 63;
    const int w       = tid >> 6;

    // coalesced stage: for fixed bn, 64 consecutive rows = 256B contiguous
#pragma unroll
    for (int i = 0; i < 16; ++i) {
        const int idx = i * 256 + tid;
        const int bn = idx >> 6, r = idx & 63;
        p1s[r][bn] = partial1[(size_t)bn * BNROWS + rowbase + r];
        p2s[r][bn] = partial2[(size_t)bn * BNROWS + rowbase + r];
    }
    __syncthreads();

    // per-wave: 16 rows, fully wave-local (select + rescore)
    for (int rr = 0; rr < 16; ++rr) {
        const int r    = w * 16 + rr;
        const int rowg = rowbase + r;

        const unsigned v1 = p1s[r][lane];
        const unsigned v2 = p2s[r][lane];

        unsigned g = v1;
#pragma unroll
        for (int mm = 1; mm < 64; mm <<= 1) g = min(g, (unsigned)__shfl_xor(g, mm));
        const unsigned thr = (((g >> 8) + MARGIN_INT) << 8) | 0xFFu;

        const u64 m1 = __ballot(v1 <= thr);
        const u64 m2 = __ballot(v2 <= thr);
        const int n1 = (int)__popcll(m1);
        const u64 below = (lane == 0) ? 0ull : ((1ull << lane) - 1ull);
        if (v1 <= thr) {
            const int slot = (int)__popcll(m1 & below);
            if (slot < 32) cands[r][slot] = lane * 256 + (int)(v1 & 0xFFu);
        }
        if (v2 <= thr) {
            const int slot = n1 + (int)__popcll(m2 & below);
            if (slot < 32) cands[r][slot] = lane * 256 + (int)(v2 & 0xFFu);
        }
        const int nc = min(n1 + (int)__popcll(m2), 32);

        // wave-parallel exact rescore (same-wave LDS writes are in-order)
        const float4 zv = ((const float4*)z)[(size_t)rowg * 64 + lane];
        u64 best = ~0ull;
        for (int c = 0; c < nc; ++c) {
            const int k = cands[r][c];
            const float4 ev = ((const float4*)emb)[(size_t)k * 64 + lane];
            float p = zv.x * ev.x;
            p = fmaf(zv.y, ev.y, p);
            p = fmaf(zv.z, ev.z, p);
            p = fmaf(zv.w, ev.w, p);
#pragma unroll
            for (int mm = 1; mm < 64; mm <<= 1) p += __shfl_xor(p, mm);
            const float sc = fmaf(-2.f, p, s[k]);
            const u64 pk = ((u64)fmap(sc) << 32) | (unsigned)k;
            best = (pk < best) ? pk : best;
        }
        if (lane == 0) {
            const int kb = (int)(best & 0xffffffffu);
            kfin[r] = kb;
            outidx[rowg] = (float)kb;
        }
    }
    __syncthreads();

    // finalize: outz copy + outq gather, float4 coalesced
#pragma unroll
    for (int i = 0; i < 16; ++i) {
        const int idx = i * 256 + tid;
        const int r = idx >> 6, c4 = idx & 63;
        const size_t rowg = (size_t)(rowbase + r);
        ((float4*)outz)[rowg * 64 + c4] = ((const float4*)z)[rowg * 64 + c4];
        ((float4*)outq)[rowg * 64 + c4] =
            ((const float4*)emb)[(size_t)kfin[r] * 64 + c4];
    }
}

extern "C" void kernel_launch(void* const* d_in, const int* in_sizes, int n_in,
                              void* d_out, int out_size, void* d_ws, size_t ws_size,
                              hipStream_t stream)
{
    const float* z  = (const float*)d_in[0];
    const float* ew = (const float*)d_in[1];
    const float* pw = (const float*)d_in[2];
    const float* pb = (const float*)d_in[3];

    float* out     = (float*)d_out;
    float* out_z   = out;                                  // (B,N,D)
    float* out_emb = out + (size_t)BNROWS * D;             // (K,D)
    float* out_q   = out + 2 * (size_t)BNROWS * D;         // (B,N,D)
    float* out_idx = out + 3 * (size_t)BNROWS * D;         // (B,N) as float

    // ws: s 64KB | s_bi 64KB | z8 4MB | partial1 4MB | partial2 4MB
    float*       sbuf  = (float*)d_ws;
    int*         s_bi  = (int*)((char*)d_ws + 65536);
    signed char* z8    = (signed char*)((char*)d_ws + 131072);
    unsigned*    part1 = (unsigned*)((char*)d_ws + 131072 + 4194304);
    unsigned*    part2 = (unsigned*)((char*)d_ws + 131072 + 2 * 4194304);
    // e8 (4 MB) lives in out_q (16 MB), overwritten by collect afterwards
    signed char* e8    = (signed char*)out_q;

    prep_kernel<<<4096 + 1024, 256, 0, stream>>>(z, z8, ew, pw, pb, out_emb, e8);
    snorm_kernel<<<KCB / 64, 256, 0, stream>>>(out_emb, sbuf, s_bi);
    argmin_hi_kernel<<<512, 512, 0, stream>>>(z8, e8, s_bi, part1, part2);
    collect_rescore_kernel<<<256, 256, 0, stream>>>(
        part1, part2, z, out_emb, sbuf, out_z, out_q, out_idx);
}

// Round 21
// 177.406 us; speedup vs baseline: 1.0876x; 1.0876x over previous
//
#include <hip/hip_runtime.h>
#include <hip/hip_bf16.h>

#define D       256
#define KCB     16384
#define BNROWS  16384
#define MARGIN  0.15f        // ~6.5 sigma of i8 screening noise
#define ZMAX    5.0f
#define EMAX    0.2f
// FS2U = 2*(ZMAX/127)*(EMAX/127) = 1.2400e-4 ; MARGIN_INT = ceil(MARGIN/FS2U)
#define FS2U    (2.0f * (ZMAX / 127.0f) * (EMAX / 127.0f))
#define MARGIN_INT 1210u
#define IBIAS   8388608      // 2^23

typedef __attribute__((ext_vector_type(4))) int   int4v;
typedef __attribute__((ext_vector_type(4))) float f32x4;
typedef unsigned long long u64;

__device__ __forceinline__ void gload_lds16(const void* g, void* l) {
    __builtin_amdgcn_global_load_lds(
        (const __attribute__((address_space(1))) void*)g,
        (__attribute__((address_space(3))) void*)l, 16, 0, 0);
}

// order-preserving float->u32 map (used only in exact rescore)
__device__ __forceinline__ unsigned fmap(float f) {
    unsigned u = __float_as_uint(f);
    return (u & 0x80000000u) ? ~u : (u | 0x80000000u);
}

__device__ __forceinline__ signed char q8(float x, float s) {
    return (signed char)__float2int_rn(fminf(fmaxf(x * s, -127.f), 127.f));
}

// ---------------------------------------------------------------------------
// prep: blocks [0,4096) -> zquant; blocks [4096,5120) -> proj + fused e8.
// ---------------------------------------------------------------------------
__global__ __launch_bounds__(256) void prep_kernel(
    const float* __restrict__ z, signed char* __restrict__ z8,
    const float* __restrict__ ew, const float* __restrict__ pw,
    const float* __restrict__ pb, float* __restrict__ emb,
    signed char* __restrict__ e8)
{
    __shared__ float Et[64][65];
    __shared__ float Pt[64][65];
    const int tid = threadIdx.x;

    if (blockIdx.x < 4096) {
        const int i = blockIdx.x * 256 + tid;
        float4 v = ((const float4*)z)[i];
        const float s = 127.0f / ZMAX;
        char4 c;
        c.x = q8(v.x, s); c.y = q8(v.y, s); c.z = q8(v.z, s); c.w = q8(v.w, s);
        ((char4*)z8)[i] = c;
        return;
    }

    const int bid = blockIdx.x - 4096;
    const int tc  = tid & 15, tr = tid >> 4;
    const int k0  = (bid >> 2) * 64;
    const int d0  = (bid & 3) * 64;

    float acc[4][4];
#pragma unroll
    for (int a = 0; a < 4; ++a)
#pragma unroll
        for (int b = 0; b < 4; ++b) acc[a][b] = 0.f;

    for (int j0 = 0; j0 < 256; j0 += 64) {
        __syncthreads();
#pragma unroll
        for (int i = 0; i < 4; ++i) {
            const int c = i * 256 + tid;
            const int r = c >> 4, c4 = (c & 15) * 4;
            float4 v = *(const float4*)(ew + (size_t)(k0 + r) * 256 + j0 + c4);
            Et[r][c4 + 0] = v.x; Et[r][c4 + 1] = v.y;
            Et[r][c4 + 2] = v.z; Et[r][c4 + 3] = v.w;
            float4 w = *(const float4*)(pw + (size_t)(d0 + r) * 256 + j0 + c4);
            Pt[r][c4 + 0] = w.x; Pt[r][c4 + 1] = w.y;
            Pt[r][c4 + 2] = w.z; Pt[r][c4 + 3] = w.w;
        }
        __syncthreads();
        for (int j = 0; j < 64; ++j) {
            float ev[4], pv[4];
#pragma unroll
            for (int a = 0; a < 4; ++a) ev[a] = Et[tr * 4 + a][j];
#pragma unroll
            for (int b = 0; b < 4; ++b) pv[b] = Pt[tc * 4 + b][j];
#pragma unroll
            for (int a = 0; a < 4; ++a)
#pragma unroll
                for (int b = 0; b < 4; ++b)
                    acc[a][b] = fmaf(ev[a], pv[b], acc[a][b]);
        }
    }

    const float4 bias = *(const float4*)(pb + d0 + tc * 4);
    const float se = 127.0f / EMAX;
#pragma unroll
    for (int a = 0; a < 4; ++a) {
        float4 o;
        o.x = acc[a][0] + bias.x; o.y = acc[a][1] + bias.y;
        o.z = acc[a][2] + bias.z; o.w = acc[a][3] + bias.w;
        const size_t off = (size_t)(k0 + tr * 4 + a) * 256 + d0 + tc * 4;
        *(float4*)(emb + off) = o;
        char4 c;
        c.x = q8(o.x, se); c.y = q8(o.y, se);
        c.z = q8(o.z, se); c.w = q8(o.w, se);
        *(char4*)(e8 + off) = c;
    }
}

// ---------------------------------------------------------------------------
// snorm: s[k] = ||emb[k]||^2 and s_bi[k] = round(s/FS2U) + 2^23.
// ---------------------------------------------------------------------------
__global__ __launch_bounds__(256) void snorm_kernel(
    const float* __restrict__ emb, float* __restrict__ s,
    int* __restrict__ s_bi)
{
    const int tid = threadIdx.x;
    const int row = blockIdx.x * 64 + (tid >> 2);
    const int qd  = tid & 3;
    const size_t base = (size_t)row * 256;
    float sq = 0.f;
#pragma unroll
    for (int j = 0; j < 16; ++j) {
        const int off = qd * 4 + j * 16;
        float4 v = *(const float4*)(emb + base + off);
        sq = fmaf(v.x, v.x, fmaf(v.y, v.y, fmaf(v.z, v.z, fmaf(v.w, v.w, sq))));
    }
    sq += __shfl_xor(sq, 1);
    sq += __shfl_xor(sq, 2);
    if (qd == 0) {
        s[row]    = sq;
        s_bi[row] = (int)rintf(sq / FS2U) + IBIAS;
    }
}

// ---------------------------------------------------------------------------
// argmin_hi v19 (frozen): persistent blocks, B panel LDS-resident.
// 512 blocks (2/CU), each pinned to one bn (4 x 16KB resident e8 tiles,
// staged once) walking 16 bm pairs; A double-buffered, pair-to-pair pipeline.
// ---------------------------------------------------------------------------
__global__ __launch_bounds__(512, 4) void argmin_hi_kernel(
    const signed char* __restrict__ z8, const signed char* __restrict__ e8,
    const int* __restrict__ s_bi,
    unsigned* __restrict__ partial1, unsigned* __restrict__ partial2)
{
    __shared__ alignas(16) short A_lds[2 * 4096];   // 2 bufs x 8 KB (128 z-rows)
    __shared__ alignas(16) short B_lds[4 * 8192];   // 4 RESIDENT tiles x 16 KB

    const int tid  = threadIdx.x;
    const int lane = tid & 63;
    const int wid  = tid >> 6;
    const int wz   = wid >> 2;
    const int wc   = wid & 3;
    const int lcol = lane & 15;
    const int rhi  = lane >> 4;

    const int bn  = blockIdx.x & 63;
    const int bm0 = blockIdx.x >> 6;     // 0..7
    const size_t n0 = (size_t)bn * 256;

    const int slot  = (((lcol & 1) * 4 + rhi) ^ ((lcol >> 1) & 7)) << 3;
    const int aoff0 = wz * 2048 + (lcol >> 1) * 64 + slot;
    const int boff0 = wc * 2048 + (lcol >> 1) * 64 + slot;

    auto goff = [](int c) {
        const int l = c >> 3, u = (c & 7) ^ (l & 7);
        return (size_t)(2 * l + (u >> 2)) * 256 + (size_t)(u & 3) * 16;
    };
    const size_t gA  = goff(tid);
    const int    cB0 = wid * 128 + lane;
    const int    cB1 = cB0 + 64;
    const size_t gB0 = goff(cB0);
    const size_t gB1 = goff(cB1);

    const char* const e8B = (const char*)e8 + n0 * 256;
    const char*       zc  = (const char*)z8 + (size_t)bm0 * 32768;

#pragma unroll
    for (int t = 0; t < 4; ++t) {
        gload_lds16(e8B + (t << 6) + gB0, (void*)(B_lds + t * 8192 + cB0 * 8));
        gload_lds16(e8B + (t << 6) + gB1, (void*)(B_lds + t * 8192 + cB1 * 8));
    }
    gload_lds16(zc + gA,      (void*)(A_lds + tid * 8));
    gload_lds16(zc + 64 + gA, (void*)(A_lds + 4096 + tid * 8));
    asm volatile("s_waitcnt vmcnt(1)" ::: "memory");
    __builtin_amdgcn_s_barrier();

#define COMPUTE_TILE(ABUF, BT)                                                \
    {                                                                         \
        int4v bq[4];                                                          \
        _Pragma("unroll")                                                     \
        for (int n = 0; n < 4; ++n)                                           \
            bq[n] = *(const int4v*)(A_lds + (ABUF) * 4096 + aoff0 + n * 512); \
        __builtin_amdgcn_s_setprio(1);                                        \
        _Pragma("unroll")                                                     \
        for (int m = 0; m < 4; ++m) {                                         \
            const int4v am = *(const int4v*)(B_lds + (BT) * 8192 + boff0 + m * 512); \
            _Pragma("unroll")                                                 \
            for (int n = 0; n < 4; ++n)                                       \
                acc[m][n] = __builtin_amdgcn_mfma_i32_16x16x64_i8(            \
                    am, bq[n], acc[m][n], 0, 0, 0);                           \
        }                                                                     \
        __builtin_amdgcn_s_setprio(0);                                        \
    }

#pragma unroll 1
    for (int i = 0; i < 16; ++i) {
        const bool more = (i < 15);

        int4v acc[4][4];
        const int4v izero = {0, 0, 0, 0};
#pragma unroll
        for (int m = 0; m < 4; ++m)
#pragma unroll
            for (int n = 0; n < 4; ++n) acc[m][n] = izero;

        COMPUTE_TILE(0, 0)
        asm volatile("s_waitcnt vmcnt(0)" ::: "memory");
        __builtin_amdgcn_s_barrier();

        gload_lds16(zc + 128 + gA, (void*)(A_lds + tid * 8));
        COMPUTE_TILE(1, 1)
        asm volatile("s_waitcnt vmcnt(0)" ::: "memory");
        __builtin_amdgcn_s_barrier();

        gload_lds16(zc + 192 + gA, (void*)(A_lds + 4096 + tid * 8));
        COMPUTE_TILE(0, 2)
        asm volatile("s_waitcnt vmcnt(0)" ::: "memory");
        __builtin_amdgcn_s_barrier();

        if (more) gload_lds16(zc + 262144 + gA, (void*)(A_lds + tid * 8));
        COMPUTE_TILE(1, 3)
        __builtin_amdgcn_s_barrier();

        int4v sb[4];
#pragma unroll
        for (int mc = 0; mc < 4; ++mc)
            sb[mc] = *(const int4v*)(s_bi + n0 + wc * 64 + mc * 16 + rhi * 4);

        u64* cand = (u64*)(A_lds + 4096);
#pragma unroll
        for (int nz = 0; nz < 4; ++nz) {
            unsigned v[16];
#pragma unroll
            for (int mc = 0; mc < 4; ++mc) {
                const unsigned cb = (unsigned)(wc * 64 + mc * 16 + rhi * 4);
#pragma unroll
                for (int j = 0; j < 4; ++j)
                    v[mc * 4 + j] =
                        ((unsigned)(sb[mc][j] - acc[mc][nz][j]) << 8) | (cb + j);
            }
            unsigned p1 = min(v[0], v[1]), p2 = max(v[0], v[1]);
#pragma unroll
            for (int q = 1; q < 8; ++q) {
                const unsigned l = min(v[2 * q], v[2 * q + 1]);
                const unsigned h = max(v[2 * q], v[2 * q + 1]);
                const unsigned t = max(p1, l);
                p1 = min(p1, l);
                p2 = min(t, min(p2, h));
            }
#pragma unroll
            for (int mask = 16; mask <= 32; mask <<= 1) {
                const unsigned q1 = __shfl_xor(p1, mask);
                const unsigned q2 = __shfl_xor(p2, mask);
                const unsigned t  = max(p1, q1);
                p1 = min(p1, q1);
                p2 = min(t, min(p2, q2));
            }
            if (rhi == 0) {
                const int row = wz * 64 + nz * 16 + lcol;
                cand[row * 4 + wc] = (u64)p1 | ((u64)p2 << 32);
            }
        }
        __syncthreads();
        if (tid < 128) {
            const u64* c4 = cand + (size_t)tid * 4;
            u64 a = c4[0];
            unsigned p1 = (unsigned)a, p2 = (unsigned)(a >> 32);
#pragma unroll
            for (int w = 1; w < 4; ++w) {
                a = c4[w];
                const unsigned q1 = (unsigned)a, q2 = (unsigned)(a >> 32);
                const unsigned t  = max(p1, q1);
                p1 = min(p1, q1);
                p2 = min(t, min(p2, q2));
            }
            const size_t r0 = (size_t)(bm0 + 8 * i) * 128;
            partial1[(size_t)bn * BNROWS + r0 + tid] = p1;
            partial2[(size_t)bn * BNROWS + r0 + tid] = p2;
        }
        __syncthreads();

        if (more) gload_lds16(zc + 262144 + 64 + gA, (void*)(A_lds + 4096 + tid * 8));
        zc += 262144;
    }
#undef COMPUTE_TILE
}

// ---------------------------------------------------------------------------
// collect_rescore (round-19 version, restored): per-row block -- global min
// over top1s, select within MARGIN_INT, wave-parallel exact fp32 rescore,
// fused finalize (out_z copy, out_q gather, out_idx).
// The r20 batched variant regressed (-15us): partials are LLC-resident so
// the scattered reads were cheap, and 16384-block TLP hid all latency.
// ---------------------------------------------------------------------------
__global__ __launch_bounds__(256) void collect_rescore_kernel(
    const unsigned* __restrict__ partial1, const unsigned* __restrict__ partial2,
    const float* __restrict__ z, const float* __restrict__ emb,
    const float* __restrict__ s,
    float* __restrict__ outz, float* __restrict__ outq,
    float* __restrict__ outidx)
{
    __shared__ unsigned gsb;
    __shared__ int      nsel;
    __shared__ int      selk[128];
    __shared__ u64      wbest[4];
    __shared__ int      kfin;

    const int tid  = threadIdx.x;
    const int row  = blockIdx.x;
    const int lane = tid & 63;
    const int wid  = tid >> 6;

    unsigned v = 0xFFFFFFFFu;
    int vbn = 0;
    if (tid < 64)       { v = partial1[(size_t)tid * BNROWS + row];        vbn = tid; }
    else if (tid < 128) { v = partial2[(size_t)(tid - 64) * BNROWS + row]; vbn = tid - 64; }

    if (tid < 64) {
        unsigned g = v;
#pragma unroll
        for (int mm = 1; mm < 64; mm <<= 1) g = min(g, (unsigned)__shfl_xor(g, mm));
        if (tid == 0) { gsb = g; nsel = 0; }
    }
    __syncthreads();

    const unsigned thr = (((gsb >> 8) + MARGIN_INT) << 8) | 0xFFu;
    if (tid < 128 && v <= thr) {
        const int i = atomicAdd(&nsel, 1);
        selk[i] = vbn * 256 + (int)(v & 0xFFu);
    }
    __syncthreads();

    const float4 zv = *(const float4*)(z + (size_t)row * 256 + lane * 4);
    const int ns = nsel;
    u64 best = ~0ull;
    for (int i = wid; i < ns; i += 4) {
        const int k = selk[i];
        const float4 ev = *(const float4*)(emb + (size_t)k * 256 + lane * 4);
        float p = zv.x * ev.x;
        p = fmaf(zv.y, ev.y, p);
        p = fmaf(zv.z, ev.z, p);
        p = fmaf(zv.w, ev.w, p);
#pragma unroll
        for (int mm = 1; mm < 64; mm <<= 1) p += __shfl_xor(p, mm);
        const float sc = fmaf(-2.f, p, s[k]);
        const u64 pk = ((u64)fmap(sc) << 32) | (unsigned)k;
        best = (pk < best) ? pk : best;
    }
    if (lane == 0) wbest[wid] = best;
    __syncthreads();
    if (tid == 0) {
        u64 b = wbest[0];
        if (wbest[1] < b) b = wbest[1];
        if (wbest[2] < b) b = wbest[2];
        if (wbest[3] < b) b = wbest[3];
        kfin = (int)(b & 0xffffffffu);
        outidx[row] = (float)kfin;
    }
    __syncthreads();

    const int k = kfin;
    outz[(size_t)row * 256 + tid] = z[(size_t)row * 256 + tid];
    outq[(size_t)row * 256 + tid] = emb[(size_t)k * 256 + tid];
}

extern "C" void kernel_launch(void* const* d_in, const int* in_sizes, int n_in,
                              void* d_out, int out_size, void* d_ws, size_t ws_size,
                              hipStream_t stream)
{
    const float* z  = (const float*)d_in[0];
    const float* ew = (const float*)d_in[1];
    const float* pw = (const float*)d_in[2];
    const float* pb = (const float*)d_in[3];

    float* out     = (float*)d_out;
    float* out_z   = out;                                  // (B,N,D)
    float* out_emb = out + (size_t)BNROWS * D;             // (K,D)
    float* out_q   = out + 2 * (size_t)BNROWS * D;         // (B,N,D)
    float* out_idx = out + 3 * (size_t)BNROWS * D;         // (B,N) as float

    // ws: s 64KB | s_bi 64KB | z8 4MB | partial1 4MB | partial2 4MB
    float*       sbuf  = (float*)d_ws;
    int*         s_bi  = (int*)((char*)d_ws + 65536);
    signed char* z8    = (signed char*)((char*)d_ws + 131072);
    unsigned*    part1 = (unsigned*)((char*)d_ws + 131072 + 4194304);
    unsigned*    part2 = (unsigned*)((char*)d_ws + 131072 + 2 * 4194304);
    // e8 (4 MB) lives in out_q (16 MB), overwritten by collect afterwards
    signed char* e8    = (signed char*)out_q;

    prep_kernel<<<4096 + 1024, 256, 0, stream>>>(z, z8, ew, pw, pb, out_emb, e8);
    snorm_kernel<<<KCB / 64, 256, 0, stream>>>(out_emb, sbuf, s_bi);
    argmin_hi_kernel<<<512, 512, 0, stream>>>(z8, e8, s_bi, part1, part2);
    collect_rescore_kernel<<<BNROWS, 256, 0, stream>>>(
        part1, part2, z, out_emb, sbuf, out_z, out_q, out_idx);
}